// Round 17
// baseline (596.864 us; speedup 1.0000x reference)
//
#include <hip/hip_runtime.h>
#include <hip/hip_bf16.h>
#include <cstdint>
#include <cstddef>

// B=2048, D=256, H=256, N=64, F=513, 4H=1024

typedef short s16x8 __attribute__((ext_vector_type(8)));
typedef float f32x4 __attribute__((ext_vector_type(4)));
typedef int   i32x4 __attribute__((ext_vector_type(4)));

static __device__ __forceinline__ unsigned short f2b(float f){
  union{float f; unsigned int u;} v; v.f = f;
  unsigned int r = v.u + 0x7fffu + ((v.u >> 16) & 1u);   // RNE
  return (unsigned short)(r >> 16);
}
static __device__ __forceinline__ float b2f(unsigned short h){
  union{unsigned int u; float f;} v; v.u = ((unsigned int)h) << 16; return v.f;
}
static __device__ __forceinline__ unsigned int pack2(float a, float b){
  return (unsigned int)f2b(a) | ((unsigned int)f2b(b) << 16);
}
static __device__ __forceinline__ float fsig(float x){ return 1.0f / (1.0f + __expf(-x)); }
static __device__ __forceinline__ float ftanh(float x){ return 2.0f / (1.0f + __expf(-2.0f * x)) - 1.0f; }
static __device__ __forceinline__ float wred(float p){
  p += __shfl_down(p, 32); p += __shfl_down(p, 16); p += __shfl_down(p, 8);
  p += __shfl_down(p, 4);  p += __shfl_down(p, 2);  p += __shfl_down(p, 1);
  return p;
}
// async global->LDS, 16 B per lane; lds base wave-uniform, global src per-lane
static __device__ __forceinline__ void gload16(const void* g, void* lds){
  __builtin_amdgcn_global_load_lds(
      (const __attribute__((address_space(1))) unsigned int*)g,
      (__attribute__((address_space(3))) unsigned int*)lds, 16, 0, 0);
}

#define WSCALE (0.30f / 127.0f)      // W_hh i8 scale

// ---------------------------------------------------------------------------
// K0: weight prep. wfB: W_ih bf16 B-fragments, kt-major (frag = kt*64 + ct).
// wfrag8: W_hh int8 B-fragments for k_lstm. bias = b_ih+b_hh; wlast = W_ih[:,512].
// ---------------------------------------------------------------------------
__global__ __launch_bounds__(256) void k_prep(
    const float* __restrict__ wih, const float* __restrict__ whh,
    const float* __restrict__ bih, const float* __restrict__ bhh,
    unsigned short* __restrict__ wfB, signed char* __restrict__ wfrag8,
    float* __restrict__ bias, float* __restrict__ wlast){
  int id = blockIdx.x * 256 + threadIdx.x;          // grid covers 524288
  { // wfB: 1024 frags * 512 entries, kt-major
    int frag = id >> 9;
    int l = (id >> 3) & 63;
    int j = id & 7;
    int kt = frag >> 6, ct = frag & 63;
    int col = ct * 16 + (l & 15);
    int k   = kt * 32 + (l >> 4) * 8 + j;
    wfB[id] = f2b(wih[col * 513 + k]);
  }
  if (id < 262144){ // wfrag8: 512 frags * 512 entries, int8
    int frag = id >> 9;
    int lane = (id >> 3) & 63;
    int j    = id & 7;
    int w  = frag >> 6;
    int kt = (frag >> 3) & 7;
    int nt = frag & 7;
    int g  = nt >> 1, hh = nt & 1;
    int colg = g * 256 + w * 32 + hh * 16 + (lane & 15);
    int k    = kt * 32 + (lane >> 4) * 8 + j;
    int q = __float2int_rn(whh[colg * 256 + k] * (1.0f / WSCALE));
    q = q > 127 ? 127 : (q < -127 ? -127 : q);
    wfrag8[frag * 512 + lane * 8 + j] = (signed char)q;
  }
  if (id < 1024){
    bias[id]  = bih[id] + bhh[id];
    wlast[id] = wih[id * 513 + 512];
  }
}

// ---------------------------------------------------------------------------
// K1: routing (fast path = first empty slot via ballot; sims fallback kept).
// ---------------------------------------------------------------------------
__global__ __launch_bounds__(256) void k_route(
    const float* __restrict__ x, const float* __restrict__ slots,
    const float* __restrict__ delta, const int* __restrict__ filled,
    const float* __restrict__ Wq, const float* __restrict__ Wk,
    const float* __restrict__ Wv, const float* __restrict__ bv,
    int* __restrict__ idx_ws, float* __restrict__ v_ws,
    float* __restrict__ delta_out, float* __restrict__ filled_out){
  int b = blockIdx.x, tid = threadIdx.x, l = tid & 63, w = tid >> 6;
  __shared__ float xs[256], qs[256], qks[256], sims[64];
  __shared__ int sidx;
  xs[tid] = x[b * 256 + tid];
  if (tid < 64){
    unsigned long long em = __ballot(filled[b * 64 + tid] == 0);
    if (tid == 0) sidx = em ? (int)__builtin_ctzll(em) : -1;
  }
  __syncthreads();
  for (int t = 0; t < 64; ++t){
    int h = w * 64 + t;
    float pv = 0.f;
    #pragma unroll
    for (int j2 = 0; j2 < 4; ++j2)
      pv += Wv[h * 256 + l + 64 * j2] * xs[l + 64 * j2];
    pv = wred(pv);
    if (l == 0) v_ws[b * 256 + h] = pv + bv[h];
  }
  if (sidx < 0){           // rare fallback: content-based argmax
    for (int t = 0; t < 64; ++t){
      int h = w * 64 + t;
      float p = 0.f;
      #pragma unroll
      for (int j2 = 0; j2 < 4; ++j2)
        p += Wq[h * 256 + l + 64 * j2] * xs[l + 64 * j2];
      p = wred(p);
      if (l == 0) qs[h] = p;
    }
    __syncthreads();
    {
      int d = tid; float p = 0.f;
      for (int h = 0; h < 256; ++h) p += qs[h] * Wk[h * 256 + d];
      qks[d] = p;
    }
    __syncthreads();
    for (int t = 0; t < 16; ++t){
      int n = w * 16 + t;
      float p = 0.f;
      #pragma unroll
      for (int j2 = 0; j2 < 4; ++j2)
        p += slots[(size_t)(b * 64 + n) * 256 + l + 64 * j2] * qks[l + 64 * j2];
      p = wred(p);
      if (l == 0) sims[n] = p;
    }
    __syncthreads();
    if (tid == 0){
      int ic = 0; float best = sims[0];
      for (int n = 1; n < 64; ++n) if (sims[n] > best){ best = sims[n]; ic = n; }
      sidx = ic;
    }
  }
  __syncthreads();
  int id = sidx;
  if (tid == 0) idx_ws[b] = id;
  if (tid < 64){
    int n = tid; bool sel = (n == id);
    delta_out[b * 64 + n]  = sel ? 0.0f : (delta[b * 64 + n] + 1.0f);
    filled_out[b * 64 + n] = (sel || filled[b * 64 + n] != 0) ? 1.0f : 0.0f;
  }
}

// ---------------------------------------------------------------------------
// K2 v2: scatter/copy + bf16 A production (unchanged).
// ---------------------------------------------------------------------------
__global__ __launch_bounds__(256) void k_scatter(
    const float* __restrict__ x, const float* __restrict__ slots,
    const float* __restrict__ cum, const int* __restrict__ idx_ws,
    const float* __restrict__ v_ws,
    float* __restrict__ slots_out, float* __restrict__ cum_out,
    unsigned short* __restrict__ abf){
  int rg = threadIdx.x >> 6, l = threadIdx.x & 63;
  int row = blockIdx.x * 4 + rg;
  int b = row >> 6, n = row & 63;
  bool sel = (n == idx_ws[b]);
  float4 f0, f1;
  if (l < 32){
    int k0 = l * 8;
    const float* src = sel ? (v_ws + (size_t)b * 256 + k0)
                           : (slots + (size_t)row * 256 + k0);
    f0 = ((const float4*)src)[0]; f1 = ((const float4*)src)[1];
    float4* d = (float4*)(slots_out + (size_t)row * 256 + k0);
    d[0] = f0; d[1] = f1;
  } else {
    int k0 = (l - 32) * 8;
    const float4* xp = (const float4*)(x + (size_t)b * 256 + k0);
    float4 x0 = xp[0], x1 = xp[1];
    if (sel){ f0 = x0; f1 = x1; }
    else {
      const float4* cp = (const float4*)(cum + (size_t)row * 256 + k0);
      f0 = cp[0]; f1 = cp[1];
      f0.x += x0.x; f0.y += x0.y; f0.z += x0.z; f0.w += x0.w;
      f1.x += x1.x; f1.y += x1.y; f1.z += x1.z; f1.w += x1.w;
    }
    float4* d = (float4*)(cum_out + (size_t)row * 256 + k0);
    d[0] = f0; d[1] = f1;
  }
  uint4 q;
  q.x = pack2(f0.x, f0.y); q.y = pack2(f0.z, f0.w);
  q.z = pack2(f1.x, f1.y); q.w = pack2(f1.z, f1.w);
  *(uint4*)(abf + (size_t)row * 512 + l * 8) = q;   // l*8 covers both halves
}

// ---------------------------------------------------------------------------
// K3 v14: pure bf16 GEMM, 256x256 tile, 8 waves (2x4), T4 counted-vmcnt
// depth-2 pipeline. Per wave per tile: 4 DMAs (A=2, B=2) -> steady vmcnt(8).
// A layout [kq 0..3][256 rows]x16B (4KB/kq); fragment = single ds_read_b128.
// LDS 96KB: A 3x16KB @0; B 3x16KB @49152 -> 1 block/CU (counted vmcnt keeps
// loads in flight across barriers). Grid 2048 XCD-chunked (4 n-blocks of an
// m-panel share A via one XCD's L2). Epilogue: two 64KB half-staged passes.
// z0 step-major: z0[(n*2048 + b)*1024 + gc] (bf16).
// ---------------------------------------------------------------------------
__global__ __launch_bounds__(512) void k_gemm(
    const unsigned short* __restrict__ abf,
    const float* __restrict__ dlt,
    const unsigned short* __restrict__ wfB,
    const float* __restrict__ wlast, const float* __restrict__ bias,
    unsigned short* __restrict__ z0){
  extern __shared__ unsigned char L[];           // 98304 B
  int tid = threadIdx.x, l = tid & 63, w = tid >> 6;
  int bid = blockIdx.x;
  int gw = (bid & 7) * 256 + (bid >> 3);         // XCD-chunked bijection (2048)
  int n_idx = gw & 3, m_idx = gw >> 2;           // 4 n-blocks x 512 m-panels
  int m0 = m_idx * 256, n0 = n_idx * 256, bA = m0 >> 6;
  int wm = w & 1, wn = w >> 1;                   // 2 x 4 wave grid
  int cl = l & 15, lhi = l >> 4;

  auto stageA = [&](int kt, int abase){          // 16KB tile, 2 DMA/wave
    int kq = w >> 1, rbase = (w & 1) * 128;
    const unsigned short* s = abf + (size_t)(m0 + rbase + l) * 512 + kt * 32 + kq * 8;
    gload16(s,             L + abase + kq * 4096 + rbase * 16);
    gload16(s + 64 * 512,  L + abase + kq * 4096 + (rbase + 64) * 16);
  };
  auto stageB = [&](int kt, int bbase){          // 16KB tile, 2 DMA/wave
    const unsigned short* s = wfB + ((size_t)(kt * 64 + n_idx * 16 + w * 2)) * 512 + l * 8;
    gload16(s,       L + bbase + (w * 2) * 1024);
    gload16(s + 512, L + bbase + (w * 2) * 1024 + 1024);
  };

  f32x4 acc[8][4];
  #pragma unroll
  for (int mi = 0; mi < 8; ++mi)
    #pragma unroll
    for (int ni = 0; ni < 4; ++ni){ f32x4 zr = {0.f,0.f,0.f,0.f}; acc[mi][ni] = zr; }

  // prologue: stage tiles 0 and 1 (8 outstanding DMA/wave)
  stageA(0, 0);      stageB(0, 49152);
  stageA(1, 16384);  stageB(1, 49152 + 16384);

  #pragma unroll
  for (int kt = 0; kt < 16; ++kt){
    if (kt < 14){
      int nb = (kt + 2) % 3;
      stageA(kt + 2, nb * 16384);
      stageB(kt + 2, 49152 + nb * 16384);
    }
    // counted wait: tile kt's 4 DMAs (per wave) have landed; never drain to 0
    if (kt < 14)       asm volatile("s_waitcnt vmcnt(8)" ::: "memory");
    else if (kt == 14) asm volatile("s_waitcnt vmcnt(4)" ::: "memory");
    else               asm volatile("s_waitcnt vmcnt(0)" ::: "memory");
    __builtin_amdgcn_s_barrier();                // all waves' tile-kt landed
    __builtin_amdgcn_sched_barrier(0);
    int ab = (kt % 3) * 16384, bb = 49152 + (kt % 3) * 16384;
    s16x8 a[8], bf[4];
    #pragma unroll
    for (int mi = 0; mi < 8; ++mi)
      a[mi] = *(const s16x8*)(L + ab + lhi * 4096 + (wm * 128 + mi * 16 + cl) * 16);
    #pragma unroll
    for (int ni = 0; ni < 4; ++ni)
      bf[ni] = *(const s16x8*)(L + bb + (wn * 4 + ni) * 1024 + l * 16);
    #pragma unroll
    for (int ni = 0; ni < 4; ++ni)
      #pragma unroll
      for (int mi = 0; mi < 8; ++mi)
        acc[mi][ni] = __builtin_amdgcn_mfma_f32_16x16x32_bf16(a[mi], bf[ni], acc[mi][ni], 0, 0, 0);
    __builtin_amdgcn_sched_barrier(0);
    __builtin_amdgcn_s_barrier();                // reads done before buf reuse
  }

  // epilogue: two half-staged passes (rows 0..127 then 128..255)
  #pragma unroll
  for (int half = 0; half < 2; ++half){
    __syncthreads();
    if (wm == half){
      #pragma unroll
      for (int mi = 0; mi < 8; ++mi)
        #pragma unroll
        for (int reg = 0; reg < 4; ++reg){
          int row = wm * 128 + mi * 16 + lhi * 4 + reg;    // global tile row
          int rl  = row - half * 128;                      // 0..127
          float dv = dlt[bA * 64 + row];
          #pragma unroll
          for (int ni = 0; ni < 4; ++ni){
            int col = wn * 64 + ni * 16 + cl;
            int gc = n0 + col;
            float val = acc[mi][ni][reg] + dv * wlast[gc] + bias[gc];
            *(unsigned short*)(L + rl * 512 + ((col * 2) ^ ((rl & 7) << 4))) = f2b(val);
          }
        }
    }
    __syncthreads();
    #pragma unroll
    for (int rr = 0; rr < 8; ++rr){
      int id = rr * 512 + tid;                   // 4096 16B chunks (64KB)
      int rl = id >> 5, cs = id & 31;
      int row = half * 128 + rl;
      int bq = bA + (row >> 6), nq = row & 63;
      uint4 v = *(const uint4*)(L + rl * 512 + ((cs * 16) ^ ((rl & 7) << 4)));
      *(uint4*)(z0 + ((size_t)nq * 2048 + bq) * 1024 + n0 + cs * 8) = v;
    }
  }
}

// ---------------------------------------------------------------------------
// K4 v9: recurrent LSTM, int8 register-resident W_hh, 256 blocks x 8 rows,
// direct-global gate reads (unchanged from R16).
// ---------------------------------------------------------------------------
__global__ __launch_bounds__(512) void k_lstm(
    const unsigned short* __restrict__ z0,
    const signed char* __restrict__ wfrag8,
    float* __restrict__ hm){
  extern __shared__ unsigned char smem[];
  unsigned char* zhh = smem;                  // 8 x 256 x float4 = 32 KB
  unsigned char* hbf = smem + 32768;          // 16 x 256 int8 = 4 KB, swizzled
  int tid = threadIdx.x, l = tid & 63, w = tid >> 6;
  int cl = l & 15, lhi = l >> 4;
  int b0 = blockIdx.x * 8;
  int chg = tid & 255;                        // gate column (fixed per thread)
  int rb  = tid >> 8;                         // row base (0/1); rr = rb + 2i

  for (int i = tid; i < 1024; i += 512) ((unsigned int*)hbf)[i] = 0u;

  // resident weights: 64 frags x 8 B per wave (128 regs)
  long long wpin[64];
  #pragma unroll
  for (int f = 0; f < 64; ++f)
    wpin[f] = *(const long long*)(wfrag8 + ((size_t)w * 64 + f) * 512 + l * 8);

  float cst[4];
  #pragma unroll
  for (int i = 0; i < 4; ++i) cst[i] = 0.f;
  const float s_comb = WSCALE / 127.0f;       // acc_i32 -> z_hh f32
  __syncthreads();

  for (int n = 0; n < 64; ++n){
    // issue gate-input loads for THIS step early (consumed after MFMA+bounce)
    unsigned short zg[4][4];
    #pragma unroll
    for (int i = 0; i < 4; ++i){
      int rr = rb + 2 * i;
      const unsigned short* zr = z0 + ((size_t)n * 2048 + b0 + rr) * 1024 + chg;
      zg[i][0] = zr[0];
      zg[i][1] = zr[256];
      zg[i][2] = zr[512];
      zg[i][3] = zr[768];
    }
    // MFMA: z_hh = h8 @ W8^T, weights from registers (rows 8-15 zero)
    i32x4 acc[8];
    #pragma unroll
    for (int nt = 0; nt < 8; ++nt){ i32x4 zr4 = {0, 0, 0, 0}; acc[nt] = zr4; }
    #pragma unroll
    for (int kt = 0; kt < 8; ++kt){
      int byteo = cl * 256 + ((kt * 32 + lhi * 8) ^ ((cl & 7) << 3));
      long long a = *(const long long*)(hbf + byteo);
      #pragma unroll
      for (int nt = 0; nt < 8; ++nt)
        acc[nt] = __builtin_amdgcn_mfma_i32_16x16x32_i8(a, wpin[kt * 8 + nt], acc[nt], 0, 0, 0);
    }
    // bounce acc -> zhh (lanes l<32 hold the 8 real rows)
    if (l < 32){
      #pragma unroll
      for (int hh = 0; hh < 2; ++hh){
        int ch = w * 32 + hh * 16 + cl;           // h column 0..255
        #pragma unroll
        for (int reg = 0; reg < 4; ++reg){
          int rr = lhi * 4 + reg;                 // row 0..7
          float4 v;
          v.x = (float)acc[0 + hh][reg];
          v.y = (float)acc[2 + hh][reg];
          v.z = (float)acc[4 + hh][reg];
          v.w = (float)acc[6 + hh][reg];
          *(float4*)(zhh + (rr * 256 + ch) * 16) = v;
        }
      }
    }
    __syncthreads();
    // gate phase: ALL 512 threads, 4 fixed (row,col) items each
    #pragma unroll
    for (int i = 0; i < 4; ++i){
      int rr = rb + 2 * i;
      int id = rr * 256 + chg;
      float4 a4 = *(const float4*)(zhh + id * 16);
      float zi = fmaf(a4.x, s_comb, b2f(zg[i][0]));
      float zf = fmaf(a4.y, s_comb, b2f(zg[i][1]));
      float zgv = fmaf(a4.z, s_comb, b2f(zg[i][2]));
      float zo = fmaf(a4.w, s_comb, b2f(zg[i][3]));
      float cv = fsig(zf) * cst[i] + fsig(zi) * ftanh(zgv);
      cst[i] = cv;
      float hv = fsig(zo) * ftanh(cv);
      hbf[rr * 256 + (chg ^ ((rr & 7) << 3))] = (signed char)__float2int_rn(hv * 127.0f);
      if (n == 63) hm[(size_t)(b0 + rr) * 256 + chg] = hv;
    }
    __syncthreads();
  }
}

// ---------------------------------------------------------------------------
extern "C" void kernel_launch(void* const* d_in, const int* in_sizes, int n_in,
                              void* d_out, int out_size, void* d_ws, size_t ws_size,
                              hipStream_t stream){
  const float* x      = (const float*)d_in[0];
  const float* slots  = (const float*)d_in[2];
  const float* cum    = (const float*)d_in[3];
  const float* delta  = (const float*)d_in[4];
  const int*   filled = (const int*)d_in[5];
  const float* Wq  = (const float*)d_in[6];
  const float* Wk  = (const float*)d_in[7];
  const float* Wv  = (const float*)d_in[8];
  const float* bv  = (const float*)d_in[9];
  const float* wih = (const float*)d_in[10];
  const float* whh = (const float*)d_in[11];
  const float* bih = (const float*)d_in[12];
  const float* bhh = (const float*)d_in[13];

  float* out        = (float*)d_out;
  float* hm         = out;                 // (B,H)    524288
  float* slots_out  = out + 524288;        // (B,N,D)  33554432
  float* cum_out    = out + 34078720;      // (B,N,D)  33554432
  float* delta_out  = out + 67633152;      // (B,N)    131072
  float* filled_out = out + 67764224;      // (B,N)    131072

  char* ws = (char*)d_ws;
  int*            idx_ws  = (int*)ws;                                  // 8KB
  float*          v_ws    = (float*)(ws + 8192);                       // 2MB
  float*          bias    = (float*)(ws + 2105344);                    // 4KB
  float*          wlast   = (float*)(ws + 2109440);                    // 4KB
  unsigned short* wfB     = (unsigned short*)(ws + 2113536);           // 1MB
  signed char*    wfrag8  = (signed char*)(ws + 3162112);              // 256KB
  unsigned short* abf     = (unsigned short*)(ws + 3686400);           // 128MB
  unsigned short* z0      = (unsigned short*)(ws + 3686400 + 134217728); // 256MB

  k_prep<<<dim3(2048), dim3(256), 0, stream>>>(wih, whh, bih, bhh, wfB, wfrag8, bias, wlast);
  k_route<<<dim3(2048), dim3(256), 0, stream>>>(x, slots, delta, filled, Wq, Wk, Wv, bv,
                                                idx_ws, v_ws, delta_out, filled_out);
  k_scatter<<<dim3(32768), dim3(256), 0, stream>>>(x, slots, cum, idx_ws, v_ws,
                                                   slots_out, cum_out, abf);
  k_gemm<<<dim3(2048), dim3(512), 98304, stream>>>(abf, delta_out,
                                                   wfB, wlast, bias, z0);
  k_lstm<<<dim3(256), dim3(512), 36864, stream>>>(z0, wfrag8, hm);
}

// Round 18
// 551.846 us; speedup vs baseline: 1.0816x; 1.0816x over previous
//
#include <hip/hip_runtime.h>
#include <hip/hip_bf16.h>
#include <cstdint>
#include <cstddef>

// B=2048, D=256, H=256, N=64, F=513, 4H=1024

typedef short s16x8 __attribute__((ext_vector_type(8)));
typedef float f32x4 __attribute__((ext_vector_type(4)));
typedef int   i32x4 __attribute__((ext_vector_type(4)));

static __device__ __forceinline__ unsigned short f2b(float f){
  union{float f; unsigned int u;} v; v.f = f;
  unsigned int r = v.u + 0x7fffu + ((v.u >> 16) & 1u);   // RNE
  return (unsigned short)(r >> 16);
}
static __device__ __forceinline__ float b2f(unsigned short h){
  union{unsigned int u; float f;} v; v.u = ((unsigned int)h) << 16; return v.f;
}
static __device__ __forceinline__ unsigned int pack2(float a, float b){
  return (unsigned int)f2b(a) | ((unsigned int)f2b(b) << 16);
}
static __device__ __forceinline__ float fsig(float x){ return 1.0f / (1.0f + __expf(-x)); }
static __device__ __forceinline__ float ftanh(float x){ return 2.0f / (1.0f + __expf(-2.0f * x)) - 1.0f; }
static __device__ __forceinline__ float wred(float p){
  p += __shfl_down(p, 32); p += __shfl_down(p, 16); p += __shfl_down(p, 8);
  p += __shfl_down(p, 4);  p += __shfl_down(p, 2);  p += __shfl_down(p, 1);
  return p;
}
// async global->LDS, 16 B per lane; lds base wave-uniform, global src per-lane
static __device__ __forceinline__ void gload16(const void* g, void* lds){
  __builtin_amdgcn_global_load_lds(
      (const __attribute__((address_space(1))) unsigned int*)g,
      (__attribute__((address_space(3))) unsigned int*)lds, 16, 0, 0);
}

#define WSCALE (0.30f / 127.0f)      // W_hh i8 scale

// ---------------------------------------------------------------------------
// K0: weight prep. wfB: W_ih bf16 B-fragments, kt-major (frag = kt*64 + ct).
// wfrag8: W_hh int8 B-fragments for k_lstm. bias = b_ih+b_hh; wlast = W_ih[:,512].
// ---------------------------------------------------------------------------
__global__ __launch_bounds__(256) void k_prep(
    const float* __restrict__ wih, const float* __restrict__ whh,
    const float* __restrict__ bih, const float* __restrict__ bhh,
    unsigned short* __restrict__ wfB, signed char* __restrict__ wfrag8,
    float* __restrict__ bias, float* __restrict__ wlast){
  int id = blockIdx.x * 256 + threadIdx.x;          // grid covers 524288
  { // wfB: 1024 frags * 512 entries, kt-major
    int frag = id >> 9;
    int l = (id >> 3) & 63;
    int j = id & 7;
    int kt = frag >> 6, ct = frag & 63;
    int col = ct * 16 + (l & 15);
    int k   = kt * 32 + (l >> 4) * 8 + j;
    wfB[id] = f2b(wih[col * 513 + k]);
  }
  if (id < 262144){ // wfrag8: 512 frags * 512 entries, int8
    int frag = id >> 9;
    int lane = (id >> 3) & 63;
    int j    = id & 7;
    int w  = frag >> 6;
    int kt = (frag >> 3) & 7;
    int nt = frag & 7;
    int g  = nt >> 1, hh = nt & 1;
    int colg = g * 256 + w * 32 + hh * 16 + (lane & 15);
    int k    = kt * 32 + (lane >> 4) * 8 + j;
    int q = __float2int_rn(whh[colg * 256 + k] * (1.0f / WSCALE));
    q = q > 127 ? 127 : (q < -127 ? -127 : q);
    wfrag8[frag * 512 + lane * 8 + j] = (signed char)q;
  }
  if (id < 1024){
    bias[id]  = bih[id] + bhh[id];
    wlast[id] = wih[id * 513 + 512];
  }
}

// ---------------------------------------------------------------------------
// K1: routing (fast path = first empty slot via ballot; sims fallback kept).
// ---------------------------------------------------------------------------
__global__ __launch_bounds__(256) void k_route(
    const float* __restrict__ x, const float* __restrict__ slots,
    const float* __restrict__ delta, const int* __restrict__ filled,
    const float* __restrict__ Wq, const float* __restrict__ Wk,
    const float* __restrict__ Wv, const float* __restrict__ bv,
    int* __restrict__ idx_ws, float* __restrict__ v_ws,
    float* __restrict__ delta_out, float* __restrict__ filled_out){
  int b = blockIdx.x, tid = threadIdx.x, l = tid & 63, w = tid >> 6;
  __shared__ float xs[256], qs[256], qks[256], sims[64];
  __shared__ int sidx;
  xs[tid] = x[b * 256 + tid];
  if (tid < 64){
    unsigned long long em = __ballot(filled[b * 64 + tid] == 0);
    if (tid == 0) sidx = em ? (int)__builtin_ctzll(em) : -1;
  }
  __syncthreads();
  for (int t = 0; t < 64; ++t){
    int h = w * 64 + t;
    float pv = 0.f;
    #pragma unroll
    for (int j2 = 0; j2 < 4; ++j2)
      pv += Wv[h * 256 + l + 64 * j2] * xs[l + 64 * j2];
    pv = wred(pv);
    if (l == 0) v_ws[b * 256 + h] = pv + bv[h];
  }
  if (sidx < 0){           // rare fallback: content-based argmax
    for (int t = 0; t < 64; ++t){
      int h = w * 64 + t;
      float p = 0.f;
      #pragma unroll
      for (int j2 = 0; j2 < 4; ++j2)
        p += Wq[h * 256 + l + 64 * j2] * xs[l + 64 * j2];
      p = wred(p);
      if (l == 0) qs[h] = p;
    }
    __syncthreads();
    {
      int d = tid; float p = 0.f;
      for (int h = 0; h < 256; ++h) p += qs[h] * Wk[h * 256 + d];
      qks[d] = p;
    }
    __syncthreads();
    for (int t = 0; t < 16; ++t){
      int n = w * 16 + t;
      float p = 0.f;
      #pragma unroll
      for (int j2 = 0; j2 < 4; ++j2)
        p += slots[(size_t)(b * 64 + n) * 256 + l + 64 * j2] * qks[l + 64 * j2];
      p = wred(p);
      if (l == 0) sims[n] = p;
    }
    __syncthreads();
    if (tid == 0){
      int ic = 0; float best = sims[0];
      for (int n = 1; n < 64; ++n) if (sims[n] > best){ best = sims[n]; ic = n; }
      sidx = ic;
    }
  }
  __syncthreads();
  int id = sidx;
  if (tid == 0) idx_ws[b] = id;
  if (tid < 64){
    int n = tid; bool sel = (n == id);
    delta_out[b * 64 + n]  = sel ? 0.0f : (delta[b * 64 + n] + 1.0f);
    filled_out[b * 64 + n] = (sel || filled[b * 64 + n] != 0) ? 1.0f : 0.0f;
  }
}

// ---------------------------------------------------------------------------
// K2 v2: scatter/copy + bf16 A production (unchanged).
// ---------------------------------------------------------------------------
__global__ __launch_bounds__(256) void k_scatter(
    const float* __restrict__ x, const float* __restrict__ slots,
    const float* __restrict__ cum, const int* __restrict__ idx_ws,
    const float* __restrict__ v_ws,
    float* __restrict__ slots_out, float* __restrict__ cum_out,
    unsigned short* __restrict__ abf){
  int rg = threadIdx.x >> 6, l = threadIdx.x & 63;
  int row = blockIdx.x * 4 + rg;
  int b = row >> 6, n = row & 63;
  bool sel = (n == idx_ws[b]);
  float4 f0, f1;
  if (l < 32){
    int k0 = l * 8;
    const float* src = sel ? (v_ws + (size_t)b * 256 + k0)
                           : (slots + (size_t)row * 256 + k0);
    f0 = ((const float4*)src)[0]; f1 = ((const float4*)src)[1];
    float4* d = (float4*)(slots_out + (size_t)row * 256 + k0);
    d[0] = f0; d[1] = f1;
  } else {
    int k0 = (l - 32) * 8;
    const float4* xp = (const float4*)(x + (size_t)b * 256 + k0);
    float4 x0 = xp[0], x1 = xp[1];
    if (sel){ f0 = x0; f1 = x1; }
    else {
      const float4* cp = (const float4*)(cum + (size_t)row * 256 + k0);
      f0 = cp[0]; f1 = cp[1];
      f0.x += x0.x; f0.y += x0.y; f0.z += x0.z; f0.w += x0.w;
      f1.x += x1.x; f1.y += x1.y; f1.z += x1.z; f1.w += x1.w;
    }
    float4* d = (float4*)(cum_out + (size_t)row * 256 + k0);
    d[0] = f0; d[1] = f1;
  }
  uint4 q;
  q.x = pack2(f0.x, f0.y); q.y = pack2(f0.z, f0.w);
  q.z = pack2(f1.x, f1.y); q.w = pack2(f1.z, f1.w);
  *(uint4*)(abf + (size_t)row * 512 + l * 8) = q;   // l*8 covers both halves
}

// ---------------------------------------------------------------------------
// K3 v15: pure bf16 GEMM, 128x256 tile, 8 waves, T4 counted-vmcnt depth-2
// pipeline, SINGLE barrier per phase. Stage for tile kt+2 is issued AFTER
// phase kt's barrier: all waves have then finished phase kt-1, so buffer
// (kt+2)%3 (last read in kt-1) is provably idle -> WAR barrier removed.
// Steady wait vmcnt(3) (tile kt's 3 DMAs of 6 outstanding). 73728B LDS ->
// 2 blocks/CU. Grid 4096 XCD-chunked. Extra __syncthreads before epilogue
// reuses L (was covered by the removed WAR barrier).
// z0 step-major: z0[(n*2048 + b)*1024 + gc] (bf16).
// ---------------------------------------------------------------------------
__global__ __launch_bounds__(512) void k_gemm(
    const unsigned short* __restrict__ abf,
    const float* __restrict__ dlt,
    const unsigned short* __restrict__ wfB,
    const float* __restrict__ wlast, const float* __restrict__ bias,
    unsigned short* __restrict__ z0){
  extern __shared__ unsigned char L[];           // 73728 B
  int tid = threadIdx.x, l = tid & 63, w = tid >> 6;
  int bid = blockIdx.x;
  int gw = (bid & 7) * 512 + (bid >> 3);         // XCD-chunked bijection (4096)
  int n_idx = gw & 3, m_idx = gw >> 2;           // 4 n-blocks x 1024 m-panels
  int m0 = m_idx * 128, n0 = n_idx * 256, bA = m0 >> 6;
  int wm = w & 1, wn = w >> 1;                   // 2 x 4 wave grid
  int cl = l & 15, lhi = l >> 4;

  auto stageA = [&](int kt, int abase){          // 8KB tile, 1 DMA/wave
    const unsigned short* s = abf + (size_t)(m0 + (w & 1) * 64 + l) * 512
                              + kt * 32 + (w >> 1) * 8;
    gload16(s, L + abase + (w >> 1) * 2048 + (w & 1) * 1024);
  };
  auto stageB = [&](int kt, int bbase){          // 16KB tile, 2 DMA/wave
    const unsigned short* s = wfB + ((size_t)(kt * 64 + n_idx * 16 + w * 2)) * 512 + l * 8;
    gload16(s,       L + bbase + (w * 2) * 1024);
    gload16(s + 512, L + bbase + (w * 2) * 1024 + 1024);
  };

  f32x4 acc[4][4];
  #pragma unroll
  for (int mi = 0; mi < 4; ++mi)
    #pragma unroll
    for (int ni = 0; ni < 4; ++ni){ f32x4 zr = {0.f,0.f,0.f,0.f}; acc[mi][ni] = zr; }

  // prologue: stage tiles 0 and 1 (6 outstanding DMA/wave)
  stageA(0, 0);      stageB(0, 24576);
  stageA(1, 8192);   stageB(1, 24576 + 16384);

  #pragma unroll
  for (int kt = 0; kt < 16; ++kt){
    // counted wait: tile kt's 3 DMAs (per wave) have landed; never drain to 0
    if (kt < 15) asm volatile("s_waitcnt vmcnt(3)" ::: "memory");
    else         asm volatile("s_waitcnt vmcnt(0)" ::: "memory");
    __builtin_amdgcn_s_barrier();                // all waves' tile-kt landed
    __builtin_amdgcn_sched_barrier(0);           // nothing hoists above barrier
    if (kt < 14){                                // stage AFTER barrier: buffer
      int nb = (kt + 2) % 3;                     // (kt+2)%3 idle since kt-1
      stageA(kt + 2, nb * 8192);
      stageB(kt + 2, 24576 + nb * 16384);
    }
    int ab = (kt % 3) * 8192, bb = 24576 + (kt % 3) * 16384;
    s16x8 a[4], bf[4];
    #pragma unroll
    for (int mi = 0; mi < 4; ++mi)
      a[mi] = *(const s16x8*)(L + ab + lhi * 2048 + (wm * 64 + mi * 16 + cl) * 16);
    #pragma unroll
    for (int ni = 0; ni < 4; ++ni)
      bf[ni] = *(const s16x8*)(L + bb + (wn * 4 + ni) * 1024 + l * 16);
    #pragma unroll
    for (int ni = 0; ni < 4; ++ni)
      #pragma unroll
      for (int mi = 0; mi < 4; ++mi)
        acc[mi][ni] = __builtin_amdgcn_mfma_f32_16x16x32_bf16(a[mi], bf[ni], acc[mi][ni], 0, 0, 0);
  }
  __syncthreads();                               // all compute done before L reuse

  // epilogue: acc -> L (z-stage, 128 rows x 512 B) -> coalesced z0 stores
  float dv[4][4];
  #pragma unroll
  for (int mi = 0; mi < 4; ++mi)
    #pragma unroll
    for (int reg = 0; reg < 4; ++reg)
      dv[mi][reg] = dlt[(bA + wm) * 64 + mi * 16 + lhi * 4 + reg];
  #pragma unroll
  for (int mi = 0; mi < 4; ++mi)
    #pragma unroll
    for (int reg = 0; reg < 4; ++reg){
      int row = wm * 64 + mi * 16 + lhi * 4 + reg;
      #pragma unroll
      for (int ni = 0; ni < 4; ++ni){
        int col = wn * 64 + ni * 16 + cl;        // 0..255
        int gc = n0 + col;
        float val = acc[mi][ni][reg] + dv[mi][reg] * wlast[gc] + bias[gc];
        *(unsigned short*)(L + row * 512 + ((col * 2) ^ ((row & 7) << 4))) = f2b(val);
      }
    }
  __syncthreads();
  #pragma unroll
  for (int rr = 0; rr < 8; ++rr){
    int id = rr * 512 + tid;                     // 4096 16B chunks
    int row = id >> 5, cs = id & 31;
    int bq = bA + (row >> 6), nq = row & 63;
    uint4 v = *(const uint4*)(L + row * 512 + ((cs * 16) ^ ((row & 7) << 4)));
    *(uint4*)(z0 + ((size_t)nq * 2048 + bq) * 1024 + n0 + cs * 8) = v;
  }
}

// ---------------------------------------------------------------------------
// K4 v9: recurrent LSTM, int8 register-resident W_hh, 256 blocks x 8 rows,
// direct-global gate reads (unchanged from R16).
// ---------------------------------------------------------------------------
__global__ __launch_bounds__(512) void k_lstm(
    const unsigned short* __restrict__ z0,
    const signed char* __restrict__ wfrag8,
    float* __restrict__ hm){
  extern __shared__ unsigned char smem[];
  unsigned char* zhh = smem;                  // 8 x 256 x float4 = 32 KB
  unsigned char* hbf = smem + 32768;          // 16 x 256 int8 = 4 KB, swizzled
  int tid = threadIdx.x, l = tid & 63, w = tid >> 6;
  int cl = l & 15, lhi = l >> 4;
  int b0 = blockIdx.x * 8;
  int chg = tid & 255;                        // gate column (fixed per thread)
  int rb  = tid >> 8;                         // row base (0/1); rr = rb + 2i

  for (int i = tid; i < 1024; i += 512) ((unsigned int*)hbf)[i] = 0u;

  // resident weights: 64 frags x 8 B per wave (128 regs)
  long long wpin[64];
  #pragma unroll
  for (int f = 0; f < 64; ++f)
    wpin[f] = *(const long long*)(wfrag8 + ((size_t)w * 64 + f) * 512 + l * 8);

  float cst[4];
  #pragma unroll
  for (int i = 0; i < 4; ++i) cst[i] = 0.f;
  const float s_comb = WSCALE / 127.0f;       // acc_i32 -> z_hh f32
  __syncthreads();

  for (int n = 0; n < 64; ++n){
    // issue gate-input loads for THIS step early (consumed after MFMA+bounce)
    unsigned short zg[4][4];
    #pragma unroll
    for (int i = 0; i < 4; ++i){
      int rr = rb + 2 * i;
      const unsigned short* zr = z0 + ((size_t)n * 2048 + b0 + rr) * 1024 + chg;
      zg[i][0] = zr[0];
      zg[i][1] = zr[256];
      zg[i][2] = zr[512];
      zg[i][3] = zr[768];
    }
    // MFMA: z_hh = h8 @ W8^T, weights from registers (rows 8-15 zero)
    i32x4 acc[8];
    #pragma unroll
    for (int nt = 0; nt < 8; ++nt){ i32x4 zr4 = {0, 0, 0, 0}; acc[nt] = zr4; }
    #pragma unroll
    for (int kt = 0; kt < 8; ++kt){
      int byteo = cl * 256 + ((kt * 32 + lhi * 8) ^ ((cl & 7) << 3));
      long long a = *(const long long*)(hbf + byteo);
      #pragma unroll
      for (int nt = 0; nt < 8; ++nt)
        acc[nt] = __builtin_amdgcn_mfma_i32_16x16x32_i8(a, wpin[kt * 8 + nt], acc[nt], 0, 0, 0);
    }
    // bounce acc -> zhh (lanes l<32 hold the 8 real rows)
    if (l < 32){
      #pragma unroll
      for (int hh = 0; hh < 2; ++hh){
        int ch = w * 32 + hh * 16 + cl;           // h column 0..255
        #pragma unroll
        for (int reg = 0; reg < 4; ++reg){
          int rr = lhi * 4 + reg;                 // row 0..7
          float4 v;
          v.x = (float)acc[0 + hh][reg];
          v.y = (float)acc[2 + hh][reg];
          v.z = (float)acc[4 + hh][reg];
          v.w = (float)acc[6 + hh][reg];
          *(float4*)(zhh + (rr * 256 + ch) * 16) = v;
        }
      }
    }
    __syncthreads();
    // gate phase: ALL 512 threads, 4 fixed (row,col) items each
    #pragma unroll
    for (int i = 0; i < 4; ++i){
      int rr = rb + 2 * i;
      int id = rr * 256 + chg;
      float4 a4 = *(const float4*)(zhh + id * 16);
      float zi = fmaf(a4.x, s_comb, b2f(zg[i][0]));
      float zf = fmaf(a4.y, s_comb, b2f(zg[i][1]));
      float zgv = fmaf(a4.z, s_comb, b2f(zg[i][2]));
      float zo = fmaf(a4.w, s_comb, b2f(zg[i][3]));
      float cv = fsig(zf) * cst[i] + fsig(zi) * ftanh(zgv);
      cst[i] = cv;
      float hv = fsig(zo) * ftanh(cv);
      hbf[rr * 256 + (chg ^ ((rr & 7) << 3))] = (signed char)__float2int_rn(hv * 127.0f);
      if (n == 63) hm[(size_t)(b0 + rr) * 256 + chg] = hv;
    }
    __syncthreads();
  }
}

// ---------------------------------------------------------------------------
extern "C" void kernel_launch(void* const* d_in, const int* in_sizes, int n_in,
                              void* d_out, int out_size, void* d_ws, size_t ws_size,
                              hipStream_t stream){
  const float* x      = (const float*)d_in[0];
  const float* slots  = (const float*)d_in[2];
  const float* cum    = (const float*)d_in[3];
  const float* delta  = (const float*)d_in[4];
  const int*   filled = (const int*)d_in[5];
  const float* Wq  = (const float*)d_in[6];
  const float* Wk  = (const float*)d_in[7];
  const float* Wv  = (const float*)d_in[8];
  const float* bv  = (const float*)d_in[9];
  const float* wih = (const float*)d_in[10];
  const float* whh = (const float*)d_in[11];
  const float* bih = (const float*)d_in[12];
  const float* bhh = (const float*)d_in[13];

  float* out        = (float*)d_out;
  float* hm         = out;                 // (B,H)    524288
  float* slots_out  = out + 524288;        // (B,N,D)  33554432
  float* cum_out    = out + 34078720;      // (B,N,D)  33554432
  float* delta_out  = out + 67633152;      // (B,N)    131072
  float* filled_out = out + 67764224;      // (B,N)    131072

  char* ws = (char*)d_ws;
  int*            idx_ws  = (int*)ws;                                  // 8KB
  float*          v_ws    = (float*)(ws + 8192);                       // 2MB
  float*          bias    = (float*)(ws + 2105344);                    // 4KB
  float*          wlast   = (float*)(ws + 2109440);                    // 4KB
  unsigned short* wfB     = (unsigned short*)(ws + 2113536);           // 1MB
  signed char*    wfrag8  = (signed char*)(ws + 3162112);              // 256KB
  unsigned short* abf     = (unsigned short*)(ws + 3686400);           // 128MB
  unsigned short* z0      = (unsigned short*)(ws + 3686400 + 134217728); // 256MB

  k_prep<<<dim3(2048), dim3(256), 0, stream>>>(wih, whh, bih, bhh, wfB, wfrag8, bias, wlast);
  k_route<<<dim3(2048), dim3(256), 0, stream>>>(x, slots, delta, filled, Wq, Wk, Wv, bv,
                                                idx_ws, v_ws, delta_out, filled_out);
  k_scatter<<<dim3(32768), dim3(256), 0, stream>>>(x, slots, cum, idx_ws, v_ws,
                                                   slots_out, cum_out, abf);
  k_gemm<<<dim3(4096), dim3(512), 73728, stream>>>(abf, delta_out,
                                                   wfB, wlast, bias, z0);
  k_lstm<<<dim3(256), dim3(512), 36864, stream>>>(z0, wfrag8, hm);
}